// Round 1
// baseline (569.106 us; speedup 1.0000x reference)
//
#include <hip/hip_runtime.h>
#include <math.h>

#define BATCH 128
#define WIN   128      // WINDOW = time steps / conv groups
#define NF    128      // conv spatial length
#define KC    16
#define POOL  65
#define NFC1  32       // number of LSTMs
#define HS    32       // hidden size

__device__ __forceinline__ float sigf(float x) { return 1.f / (1.f + __expf(-x)); }
__device__ __forceinline__ float tanh_fast(float x) {
    float xc = fminf(fmaxf(x, -15.f), 15.f);
    float t = __expf(-2.f * xc);
    return (1.f - t) / (1.f + t);
}
__device__ __forceinline__ float lstm_cell(float& c, const float4 g) {
    float ig = sigf(g.x), fg = sigf(g.y), gg = tanh_fast(g.z), og = sigf(g.w);
    c = fg * c + ig * gg;
    return og * tanh_fast(c);
}
__device__ __forceinline__ void fma4(float4& a, const float4 w, const float s) {
    a.x = fmaf(w.x, s, a.x); a.y = fmaf(w.y, s, a.y);
    a.z = fmaf(w.z, s, a.z); a.w = fmaf(w.w, s, a.w);
}

// ---------------- K1: grouped conv1d + relu + maxpool(2,2,pad1) + fc1 ----------------
// grid = WIN*16 blocks; block handles (w, 8 batches); 256 threads.
// z output layout: [t=w][f=o][b]
__global__ __launch_bounds__(256) void k1_conv_fc1(
    const float* __restrict__ x, const float* __restrict__ conv_w, const float* __restrict__ conv_b,
    const float* __restrict__ fc1_w, const float* __restrict__ fc1_b, float* __restrict__ z)
{
    __shared__ float xp[8][NF + 2];          // zero-padded input rows
    __shared__ float pool[8][KC * POOL];     // 8 x 1040
    __shared__ float cw[KC][3];
    __shared__ float cb[KC];

    const int w = blockIdx.x >> 4;
    const int bbase = (blockIdx.x & 15) * 8;
    const int tid = threadIdx.x;

    if (tid < KC * 3) cw[tid / 3][tid % 3] = conv_w[(w * KC + tid / 3) * 3 + tid % 3];
    if (tid < KC) cb[tid] = conv_b[w * KC + tid];

    for (int i = tid; i < 8 * (NF + 2); i += 256) {
        int b = i / (NF + 2), p = i % (NF + 2);
        float v = 0.f;
        if (p >= 1 && p <= NF) v = x[(size_t)(bbase + b) * WIN * NF + (size_t)w * NF + (p - 1)];
        xp[b][p] = v;
    }
    __syncthreads();

    // conv + relu + maxpool: pool[j] = max over positions {2j-1, 2j} (pads lose since relu>=0)
    for (int i = tid; i < 8 * KC * POOL; i += 256) {
        int b = i / (KC * POOL);
        int r = i % (KC * POOL);
        int k = r / POOL, j = r % POOL;
        float w0 = cw[k][0], w1 = cw[k][1], w2 = cw[k][2], bb = cb[k];
        int p0 = 2 * j - 1, p1 = 2 * j;
        float m = 0.f;  // relu floor
        if (p0 >= 0) {
            float v = bb + w0 * xp[b][p0] + w1 * xp[b][p0 + 1] + w2 * xp[b][p0 + 2];
            m = fmaxf(m, v);
        }
        if (p1 <= NF - 1) {
            float v = bb + w0 * xp[b][p1] + w1 * xp[b][p1 + 1] + w2 * xp[b][p1 + 2];
            m = fmaxf(m, v);
        }
        pool[b][k * POOL + j] = m;
    }
    __syncthreads();

    // fc1: thread -> (b = tid>>5, o = tid&31); dot length 1040 (= 260 float4)
    const int b = tid >> 5, o = tid & 31;
    const float4* w4 = (const float4*)(fc1_w + (size_t)o * (KC * POOL));
    const float4* p4 = (const float4*)(&pool[b][0]);
    float acc = fc1_b[o];
    #pragma unroll 4
    for (int i = 0; i < (KC * POOL) / 4; ++i) {
        float4 wv = w4[i], pv = p4[i];
        acc = fmaf(wv.x, pv.x, acc);
        acc = fmaf(wv.y, pv.y, acc);
        acc = fmaf(wv.z, pv.z, acc);
        acc = fmaf(wv.w, pv.w, acc);
    }
    z[(size_t)w * NFC1 * BATCH + (size_t)o * BATCH + (bbase + b)] = acc;
}

// ---------------- K2: 2-layer LSTM, seq len 128 ----------------
// grid = NFC1*16 blocks; block = (f, 8 batches); 128 threads = 4 slots x 32 elems;
// each thread handles 2 batches x 1 hidden element (4 gates as float4).
__global__ __launch_bounds__(128) void k2_lstm(
    const float* __restrict__ w_ih0, const float* __restrict__ w_ih1,
    const float* __restrict__ w_hh, const float* __restrict__ b_lstm,
    const float* __restrict__ z, float* __restrict__ h1fin)
{
    __shared__ float Wg0[HS][HS * 4];   // layer0 hh, transposed: [h][e*4+gate]
    __shared__ float Wi1[HS][HS * 4];   // layer1 ih
    __shared__ float Wh1[HS][HS * 4];   // layer1 hh
    __shared__ float bias0[HS * 4], bias1[HS * 4], wih0v[HS * 4];
    __shared__ float h0buf[8][HS], h1buf[8][HS];
    __shared__ float zl[WIN][8];

    const int f = blockIdx.x >> 4;
    const int bbase = (blockIdx.x & 15) * 8;
    const int tid = threadIdx.x;
    const int e = tid & 31, s = tid >> 5;
    const int lb0 = s * 2, lb1 = s * 2 + 1;

    // stage weights transposed: src [g][h] -> dst [h][(g&31)*4 + (g>>5)]
    const float* src0 = w_hh + (size_t)f * 4096;              // w_hh[0][f]
    const float* srcI = w_ih1 + (size_t)f * 4096;             // w_ih1[0][f]
    const float* src1 = w_hh + (size_t)(32 + f) * 4096;       // w_hh[1][f]
    for (int i = tid; i < 4096; i += 128) {
        int g = i >> 5, h = i & 31;
        int d = ((g & 31) << 2) | (g >> 5);
        Wg0[h][d] = src0[i];
        Wi1[h][d] = srcI[i];
        Wh1[h][d] = src1[i];
    }
    for (int i = tid; i < 128; i += 128) {
        int d = ((i & 31) << 2) | (i >> 5);
        bias0[d]  = b_lstm[f * 128 + i];
        bias1[d]  = b_lstm[32 * 128 + f * 128 + i];
        wih0v[d]  = w_ih0[f * 128 + i];
    }
    for (int i = tid; i < WIN * 8; i += 128) {
        int t = i >> 3, lb = i & 7;
        zl[t][lb] = z[(size_t)t * NFC1 * BATCH + f * BATCH + bbase + lb];
    }
    for (int i = tid; i < 8 * HS; i += 128) {
        ((float*)h0buf)[i] = 0.f;
        ((float*)h1buf)[i] = 0.f;
    }
    __syncthreads();

    float c0a = 0.f, c0b = 0.f, c1a = 0.f, c1b = 0.f;
    float h1a = 0.f, h1b = 0.f;

    #pragma unroll 1
    for (int t = 0; t < WIN; ++t) {
        // ----- layer 0 -----
        float xa = zl[t][lb0], xb = zl[t][lb1];
        float4 bb0 = *(const float4*)&bias0[e * 4];
        float4 wi0 = *(const float4*)&wih0v[e * 4];
        float4 ga, gb;
        ga.x = fmaf(xa, wi0.x, bb0.x); ga.y = fmaf(xa, wi0.y, bb0.y);
        ga.z = fmaf(xa, wi0.z, bb0.z); ga.w = fmaf(xa, wi0.w, bb0.w);
        gb.x = fmaf(xb, wi0.x, bb0.x); gb.y = fmaf(xb, wi0.y, bb0.y);
        gb.z = fmaf(xb, wi0.z, bb0.z); gb.w = fmaf(xb, wi0.w, bb0.w);
        #pragma unroll
        for (int hc = 0; hc < 8; ++hc) {
            float4 ha = *(const float4*)&h0buf[lb0][hc * 4];
            float4 hb = *(const float4*)&h0buf[lb1][hc * 4];
            float4 w0 = *(const float4*)&Wg0[hc * 4 + 0][e * 4];
            float4 w1 = *(const float4*)&Wg0[hc * 4 + 1][e * 4];
            float4 w2 = *(const float4*)&Wg0[hc * 4 + 2][e * 4];
            float4 w3 = *(const float4*)&Wg0[hc * 4 + 3][e * 4];
            fma4(ga, w0, ha.x); fma4(ga, w1, ha.y); fma4(ga, w2, ha.z); fma4(ga, w3, ha.w);
            fma4(gb, w0, hb.x); fma4(gb, w1, hb.y); fma4(gb, w2, hb.z); fma4(gb, w3, hb.w);
        }
        float h0a = lstm_cell(c0a, ga);
        float h0b = lstm_cell(c0b, gb);

        __syncthreads();                       // all reads of h0buf(prev) done
        h0buf[lb0][e] = h0a;
        h0buf[lb1][e] = h0b;
        float4 bb1 = *(const float4*)&bias1[e * 4];
        ga = bb1; gb = bb1;
        __syncthreads();                       // h0(new) visible

        // ----- layer 1 -----
        #pragma unroll
        for (int hc = 0; hc < 8; ++hc) {
            float4 ia = *(const float4*)&h0buf[lb0][hc * 4];
            float4 ib = *(const float4*)&h0buf[lb1][hc * 4];
            float4 pa = *(const float4*)&h1buf[lb0][hc * 4];
            float4 pb = *(const float4*)&h1buf[lb1][hc * 4];
            float4 u0 = *(const float4*)&Wi1[hc * 4 + 0][e * 4];
            float4 u1 = *(const float4*)&Wi1[hc * 4 + 1][e * 4];
            float4 u2 = *(const float4*)&Wi1[hc * 4 + 2][e * 4];
            float4 u3 = *(const float4*)&Wi1[hc * 4 + 3][e * 4];
            fma4(ga, u0, ia.x); fma4(ga, u1, ia.y); fma4(ga, u2, ia.z); fma4(ga, u3, ia.w);
            fma4(gb, u0, ib.x); fma4(gb, u1, ib.y); fma4(gb, u2, ib.z); fma4(gb, u3, ib.w);
            float4 v0 = *(const float4*)&Wh1[hc * 4 + 0][e * 4];
            float4 v1 = *(const float4*)&Wh1[hc * 4 + 1][e * 4];
            float4 v2 = *(const float4*)&Wh1[hc * 4 + 2][e * 4];
            float4 v3 = *(const float4*)&Wh1[hc * 4 + 3][e * 4];
            fma4(ga, v0, pa.x); fma4(ga, v1, pa.y); fma4(ga, v2, pa.z); fma4(ga, v3, pa.w);
            fma4(gb, v0, pb.x); fma4(gb, v1, pb.y); fma4(gb, v2, pb.z); fma4(gb, v3, pb.w);
        }
        float nh1a = lstm_cell(c1a, ga);
        float nh1b = lstm_cell(c1b, gb);

        __syncthreads();                       // all reads of h1buf(prev) done
        h1buf[lb0][e] = nh1a;
        h1buf[lb1][e] = nh1b;
        h1a = nh1a; h1b = nh1b;
    }

    // top layer, last step -> combined[b][f*HS+e]
    h1fin[(size_t)(bbase + lb0) * (NFC1 * HS) + f * HS + e] = h1a;
    h1fin[(size_t)(bbase + lb1) * (NFC1 * HS) + f * HS + e] = h1b;
}

// ---------------- K3: head (mu / logvar / CI bounds) ----------------
__global__ __launch_bounds__(128) void k3_head(
    const float* __restrict__ h1fin, const float* __restrict__ mu_w, const float* __restrict__ mu_b,
    const float* __restrict__ lv_w, const float* __restrict__ lv_b, float* __restrict__ out)
{
    const int b = blockIdx.x, tid = threadIdx.x;
    const float* hrow = h1fin + (size_t)b * (NFC1 * HS);
    float am = 0.f, al = 0.f;
    for (int i = tid; i < NFC1 * HS; i += 128) {
        float h = hrow[i];
        am = fmaf(h, mu_w[i], am);
        al = fmaf(h, lv_w[i], al);
    }
    for (int off = 32; off >= 1; off >>= 1) {
        am += __shfl_down(am, off, 64);
        al += __shfl_down(al, off, 64);
    }
    __shared__ float sm[2], sl[2];
    const int wv = tid >> 6, ln = tid & 63;
    if (ln == 0) { sm[wv] = am; sl[wv] = al; }
    __syncthreads();
    if (tid == 0) {
        float mu = sm[0] + sm[1] + mu_b[0];
        float lv = sl[0] + sl[1] + lv_b[0];
        float sg = expf(0.5f * lv);
        out[b]           = mu - 1.96f * sg;
        out[128 + b]     = mu;
        out[256 + b]     = mu + 1.96f * sg;
        out[384 + b]     = lv;
    }
}

extern "C" void kernel_launch(void* const* d_in, const int* in_sizes, int n_in,
                              void* d_out, int out_size, void* d_ws, size_t ws_size,
                              hipStream_t stream)
{
    const float* x      = (const float*)d_in[0];
    const float* conv_w = (const float*)d_in[1];
    const float* conv_b = (const float*)d_in[2];
    const float* fc1_w  = (const float*)d_in[3];
    const float* fc1_b  = (const float*)d_in[4];
    const float* w_ih0  = (const float*)d_in[5];
    const float* w_ih1  = (const float*)d_in[6];
    const float* w_hh   = (const float*)d_in[7];
    const float* b_lstm = (const float*)d_in[8];
    const float* mu_w   = (const float*)d_in[9];
    const float* mu_b   = (const float*)d_in[10];
    const float* lv_w   = (const float*)d_in[11];
    const float* lv_b   = (const float*)d_in[12];
    float* out = (float*)d_out;

    float* z     = (float*)d_ws;                         // WIN*NFC1*BATCH floats (2 MB)
    float* h1fin = z + (size_t)WIN * NFC1 * BATCH;       // BATCH*NFC1*HS floats (0.5 MB)

    k1_conv_fc1<<<dim3(WIN * 16), dim3(256), 0, stream>>>(x, conv_w, conv_b, fc1_w, fc1_b, z);
    k2_lstm<<<dim3(NFC1 * 16), dim3(128), 0, stream>>>(w_ih0, w_ih1, w_hh, b_lstm, z, h1fin);
    k3_head<<<dim3(BATCH), dim3(128), 0, stream>>>(h1fin, mu_w, mu_b, lv_w, lv_b, out);
}

// Round 2
// 547.047 us; speedup vs baseline: 1.0403x; 1.0403x over previous
//
#include <hip/hip_runtime.h>
#include <math.h>

#define BATCH 128
#define WIN   128      // WINDOW = time steps / conv groups
#define NF    128      // conv spatial length
#define KC    16
#define POOL  65
#define NFC1  32       // number of LSTMs
#define HS    32       // hidden size
#define NB    2        // batches per k2 block

// exp/rcp-based activations: no branches, correct limits at +/-inf
__device__ __forceinline__ float sigf(float x) {
    return __builtin_amdgcn_rcpf(1.f + __expf(-x));
}
__device__ __forceinline__ float tanhf_fast(float x) {
    // tanh(x) = 1 - 2/(exp(2x)+1); exp->inf gives 1, exp->0 gives -1
    float m = __expf(2.f * x);
    return fmaf(-2.f, __builtin_amdgcn_rcpf(m + 1.f), 1.f);
}
__device__ __forceinline__ float lstm_cell2(float& c, float gi, float gf, float gg, float go) {
    float si = sigf(gi), sf = sigf(gf), tg = tanhf_fast(gg), so = sigf(go);
    c = fmaf(sf, c, si * tg);
    return so * tanhf_fast(c);
}

// ---------------- K1: grouped conv1d + relu + maxpool(2,2,pad1) + fc1 ----------------
// grid = WIN*16 blocks; block handles (w, 8 batches); 256 threads.
// z output layout: [t=w][f=o][b]
__global__ __launch_bounds__(256) void k1_conv_fc1(
    const float* __restrict__ x, const float* __restrict__ conv_w, const float* __restrict__ conv_b,
    const float* __restrict__ fc1_w, const float* __restrict__ fc1_b, float* __restrict__ z)
{
    __shared__ float xp[8][NF + 2];          // zero-padded input rows
    __shared__ float pool[8][KC * POOL];     // 8 x 1040
    __shared__ float cw[KC][3];
    __shared__ float cb[KC];

    const int w = blockIdx.x >> 4;
    const int bbase = (blockIdx.x & 15) * 8;
    const int tid = threadIdx.x;

    if (tid < KC * 3) cw[tid / 3][tid % 3] = conv_w[(w * KC + tid / 3) * 3 + tid % 3];
    if (tid < KC) cb[tid] = conv_b[w * KC + tid];

    for (int i = tid; i < 8 * (NF + 2); i += 256) {
        int b = i / (NF + 2), p = i % (NF + 2);
        float v = 0.f;
        if (p >= 1 && p <= NF) v = x[(size_t)(bbase + b) * WIN * NF + (size_t)w * NF + (p - 1)];
        xp[b][p] = v;
    }
    __syncthreads();

    // conv + relu + maxpool: pool[j] = max over positions {2j-1, 2j} (pads lose since relu>=0)
    for (int i = tid; i < 8 * KC * POOL; i += 256) {
        int b = i / (KC * POOL);
        int r = i % (KC * POOL);
        int k = r / POOL, j = r % POOL;
        float w0 = cw[k][0], w1 = cw[k][1], w2 = cw[k][2], bb = cb[k];
        int p0 = 2 * j - 1, p1 = 2 * j;
        float m = 0.f;  // relu floor
        if (p0 >= 0) {
            float v = bb + w0 * xp[b][p0] + w1 * xp[b][p0 + 1] + w2 * xp[b][p0 + 2];
            m = fmaxf(m, v);
        }
        if (p1 <= NF - 1) {
            float v = bb + w0 * xp[b][p1] + w1 * xp[b][p1 + 1] + w2 * xp[b][p1 + 2];
            m = fmaxf(m, v);
        }
        pool[b][k * POOL + j] = m;
    }
    __syncthreads();

    // fc1: thread -> (b = tid>>5, o = tid&31); dot length 1040 (= 260 float4)
    const int b = tid >> 5, o = tid & 31;
    const float4* w4 = (const float4*)(fc1_w + (size_t)o * (KC * POOL));
    const float4* p4 = (const float4*)(&pool[b][0]);
    float acc = fc1_b[o];
    #pragma unroll 4
    for (int i = 0; i < (KC * POOL) / 4; ++i) {
        float4 wv = w4[i], pv = p4[i];
        acc = fmaf(wv.x, pv.x, acc);
        acc = fmaf(wv.y, pv.y, acc);
        acc = fmaf(wv.z, pv.z, acc);
        acc = fmaf(wv.w, pv.w, acc);
    }
    z[(size_t)w * NFC1 * BATCH + (size_t)o * BATCH + (bbase + b)] = acc;
}

// ---------------- K2: 2-layer LSTM, seq 128 — 1 wave/block, weights in VGPRs, 0 barriers ----------------
// grid = 32 f * 64 batch-pairs = 2048 blocks of 64 threads.
// lane = p*32 + e ; p=0 owns gate columns {i,f}, p=1 owns {g,o} for hidden elem e.
__global__ __launch_bounds__(64, 2) void k2_lstm(
    const float* __restrict__ w_ih0, const float* __restrict__ w_ih1,
    const float* __restrict__ w_hh, const float* __restrict__ b_lstm,
    const float* __restrict__ z, float* __restrict__ h1fin)
{
    __shared__ float zl[WIN][NB];
    __shared__ float h0s[NB][HS];
    __shared__ float h1s[NB][HS];

    const int f = blockIdx.x >> 6;          // 64 consecutive blocks share f -> XCD-L2 weight reuse
    const int bg = blockIdx.x & 63;
    const int bbase = bg * NB;
    const int lane = threadIdx.x;
    const int p = lane >> 5;
    const int e = lane & 31;
    const int r0 = p * 64 + e;              // gate row: p=0 -> i(e), p=1 -> g(e)
    const int r1 = p * 64 + 32 + e;         // gate row: p=0 -> f(e), p=1 -> o(e)

    // weight rows into registers: 6 rows x 32 floats = 48 float4 = 192 VGPRs
    const float* A = w_hh + (size_t)f * 4096;             // layer0 hh  [128][32]
    const float* U = w_ih1 + (size_t)f * 4096;            // layer1 ih  [128][32]
    const float* V = w_hh + (size_t)(NFC1 + f) * 4096;    // layer1 hh  [128][32]
    float4 a0[8], a1[8], u0[8], u1[8], v0[8], v1[8];
    #pragma unroll
    for (int i = 0; i < 8; ++i) {
        a0[i] = ((const float4*)(A + r0 * HS))[i];
        a1[i] = ((const float4*)(A + r1 * HS))[i];
        u0[i] = ((const float4*)(U + r0 * HS))[i];
        u1[i] = ((const float4*)(U + r1 * HS))[i];
        v0[i] = ((const float4*)(V + r0 * HS))[i];
        v1[i] = ((const float4*)(V + r1 * HS))[i];
    }
    const float b0a = b_lstm[f * 128 + r0];
    const float b0b = b_lstm[f * 128 + r1];
    const float b1a = b_lstm[NFC1 * 128 + f * 128 + r0];
    const float b1b = b_lstm[NFC1 * 128 + f * 128 + r1];
    const float wia = w_ih0[f * 128 + r0];
    const float wib = w_ih0[f * 128 + r1];

    // stage this block's z column: zl[t][b]
    for (int i = lane; i < WIN * NB; i += 64) {
        int t = i >> 1, b = i & 1;
        zl[t][b] = z[(size_t)t * NFC1 * BATCH + f * BATCH + bbase + b];
    }
    if (lane < NB * HS) { ((float*)h0s)[lane] = 0.f; ((float*)h1s)[lane] = 0.f; }
    __syncthreads();   // single wave: cheap, once

    float c0[NB] = {0.f, 0.f}, c1[NB] = {0.f, 0.f};
    float h1keep[NB] = {0.f, 0.f};

    #pragma unroll 1
    for (int t = 0; t < WIN; ++t) {
        // ----- layer 0: gates = b + wih0*x + A . h0prev -----
        float ga[NB], gb[NB];
        #pragma unroll
        for (int b = 0; b < NB; ++b) {
            float xv = zl[t][b];
            ga[b] = fmaf(xv, wia, b0a);
            gb[b] = fmaf(xv, wib, b0b);
        }
        #pragma unroll
        for (int hc = 0; hc < 8; ++hc) {
            float4 hv0 = *(const float4*)&h0s[0][hc * 4];
            float4 hv1 = *(const float4*)&h0s[1][hc * 4];
            ga[0] = fmaf(a0[hc].x, hv0.x, ga[0]); ga[0] = fmaf(a0[hc].y, hv0.y, ga[0]);
            ga[0] = fmaf(a0[hc].z, hv0.z, ga[0]); ga[0] = fmaf(a0[hc].w, hv0.w, ga[0]);
            gb[0] = fmaf(a1[hc].x, hv0.x, gb[0]); gb[0] = fmaf(a1[hc].y, hv0.y, gb[0]);
            gb[0] = fmaf(a1[hc].z, hv0.z, gb[0]); gb[0] = fmaf(a1[hc].w, hv0.w, gb[0]);
            ga[1] = fmaf(a0[hc].x, hv1.x, ga[1]); ga[1] = fmaf(a0[hc].y, hv1.y, ga[1]);
            ga[1] = fmaf(a0[hc].z, hv1.z, ga[1]); ga[1] = fmaf(a0[hc].w, hv1.w, ga[1]);
            gb[1] = fmaf(a1[hc].x, hv1.x, gb[1]); gb[1] = fmaf(a1[hc].y, hv1.y, gb[1]);
            gb[1] = fmaf(a1[hc].z, hv1.z, gb[1]); gb[1] = fmaf(a1[hc].w, hv1.w, gb[1]);
        }
        #pragma unroll
        for (int b = 0; b < NB; ++b) {
            float oa = __shfl_xor(ga[b], 32, 64);
            float ob = __shfl_xor(gb[b], 32, 64);
            float gi = p ? oa : ga[b];
            float gf = p ? ob : gb[b];
            float gg = p ? ga[b] : oa;
            float go = p ? gb[b] : ob;
            float h = lstm_cell2(c0[b], gi, gf, gg, go);
            if (p == 0) h0s[b][e] = h;          // same-wave RAW; no barrier needed
        }

        // ----- layer 1: gates = b + U . h0new + V . h1prev -----
        ga[0] = b1a; gb[0] = b1b; ga[1] = b1a; gb[1] = b1b;
        #pragma unroll
        for (int hc = 0; hc < 8; ++hc) {
            float4 hv0 = *(const float4*)&h0s[0][hc * 4];
            float4 hv1 = *(const float4*)&h0s[1][hc * 4];
            float4 pv0 = *(const float4*)&h1s[0][hc * 4];
            float4 pv1 = *(const float4*)&h1s[1][hc * 4];
            ga[0] = fmaf(u0[hc].x, hv0.x, ga[0]); ga[0] = fmaf(u0[hc].y, hv0.y, ga[0]);
            ga[0] = fmaf(u0[hc].z, hv0.z, ga[0]); ga[0] = fmaf(u0[hc].w, hv0.w, ga[0]);
            gb[0] = fmaf(u1[hc].x, hv0.x, gb[0]); gb[0] = fmaf(u1[hc].y, hv0.y, gb[0]);
            gb[0] = fmaf(u1[hc].z, hv0.z, gb[0]); gb[0] = fmaf(u1[hc].w, hv0.w, gb[0]);
            ga[0] = fmaf(v0[hc].x, pv0.x, ga[0]); ga[0] = fmaf(v0[hc].y, pv0.y, ga[0]);
            ga[0] = fmaf(v0[hc].z, pv0.z, ga[0]); ga[0] = fmaf(v0[hc].w, pv0.w, ga[0]);
            gb[0] = fmaf(v1[hc].x, pv0.x, gb[0]); gb[0] = fmaf(v1[hc].y, pv0.y, gb[0]);
            gb[0] = fmaf(v1[hc].z, pv0.z, gb[0]); gb[0] = fmaf(v1[hc].w, pv0.w, gb[0]);
            ga[1] = fmaf(u0[hc].x, hv1.x, ga[1]); ga[1] = fmaf(u0[hc].y, hv1.y, ga[1]);
            ga[1] = fmaf(u0[hc].z, hv1.z, ga[1]); ga[1] = fmaf(u0[hc].w, hv1.w, ga[1]);
            gb[1] = fmaf(u1[hc].x, hv1.x, gb[1]); gb[1] = fmaf(u1[hc].y, hv1.y, gb[1]);
            gb[1] = fmaf(u1[hc].z, hv1.z, gb[1]); gb[1] = fmaf(u1[hc].w, hv1.w, gb[1]);
            ga[1] = fmaf(v0[hc].x, pv1.x, ga[1]); ga[1] = fmaf(v0[hc].y, pv1.y, ga[1]);
            ga[1] = fmaf(v0[hc].z, pv1.z, ga[1]); ga[1] = fmaf(v0[hc].w, pv1.w, ga[1]);
            gb[1] = fmaf(v1[hc].x, pv1.x, gb[1]); gb[1] = fmaf(v1[hc].y, pv1.y, gb[1]);
            gb[1] = fmaf(v1[hc].z, pv1.z, gb[1]); gb[1] = fmaf(v1[hc].w, pv1.w, gb[1]);
        }
        #pragma unroll
        for (int b = 0; b < NB; ++b) {
            float oa = __shfl_xor(ga[b], 32, 64);
            float ob = __shfl_xor(gb[b], 32, 64);
            float gi = p ? oa : ga[b];
            float gf = p ? ob : gb[b];
            float gg = p ? ga[b] : oa;
            float go = p ? gb[b] : ob;
            float h = lstm_cell2(c1[b], gi, gf, gg, go);
            if (p == 0) h1s[b][e] = h;
            h1keep[b] = h;
        }
    }

    if (p == 0) {
        h1fin[(size_t)(bbase + 0) * (NFC1 * HS) + f * HS + e] = h1keep[0];
        h1fin[(size_t)(bbase + 1) * (NFC1 * HS) + f * HS + e] = h1keep[1];
    }
}

// ---------------- K3: head (mu / logvar / CI bounds) ----------------
__global__ __launch_bounds__(128) void k3_head(
    const float* __restrict__ h1fin, const float* __restrict__ mu_w, const float* __restrict__ mu_b,
    const float* __restrict__ lv_w, const float* __restrict__ lv_b, float* __restrict__ out)
{
    const int b = blockIdx.x, tid = threadIdx.x;
    const float* hrow = h1fin + (size_t)b * (NFC1 * HS);
    float am = 0.f, al = 0.f;
    for (int i = tid; i < NFC1 * HS; i += 128) {
        float h = hrow[i];
        am = fmaf(h, mu_w[i], am);
        al = fmaf(h, lv_w[i], al);
    }
    for (int off = 32; off >= 1; off >>= 1) {
        am += __shfl_down(am, off, 64);
        al += __shfl_down(al, off, 64);
    }
    __shared__ float sm[2], sl[2];
    const int wv = tid >> 6, ln = tid & 63;
    if (ln == 0) { sm[wv] = am; sl[wv] = al; }
    __syncthreads();
    if (tid == 0) {
        float mu = sm[0] + sm[1] + mu_b[0];
        float lv = sl[0] + sl[1] + lv_b[0];
        float sg = expf(0.5f * lv);
        out[b]           = mu - 1.96f * sg;
        out[128 + b]     = mu;
        out[256 + b]     = mu + 1.96f * sg;
        out[384 + b]     = lv;
    }
}

extern "C" void kernel_launch(void* const* d_in, const int* in_sizes, int n_in,
                              void* d_out, int out_size, void* d_ws, size_t ws_size,
                              hipStream_t stream)
{
    const float* x      = (const float*)d_in[0];
    const float* conv_w = (const float*)d_in[1];
    const float* conv_b = (const float*)d_in[2];
    const float* fc1_w  = (const float*)d_in[3];
    const float* fc1_b  = (const float*)d_in[4];
    const float* w_ih0  = (const float*)d_in[5];
    const float* w_ih1  = (const float*)d_in[6];
    const float* w_hh   = (const float*)d_in[7];
    const float* b_lstm = (const float*)d_in[8];
    const float* mu_w   = (const float*)d_in[9];
    const float* mu_b   = (const float*)d_in[10];
    const float* lv_w   = (const float*)d_in[11];
    const float* lv_b   = (const float*)d_in[12];
    float* out = (float*)d_out;

    float* z     = (float*)d_ws;                         // WIN*NFC1*BATCH floats (2 MB)
    float* h1fin = z + (size_t)WIN * NFC1 * BATCH;       // BATCH*NFC1*HS floats (0.5 MB)

    k1_conv_fc1<<<dim3(WIN * 16), dim3(256), 0, stream>>>(x, conv_w, conv_b, fc1_w, fc1_b, z);
    k2_lstm<<<dim3(NFC1 * 64), dim3(64), 0, stream>>>(w_ih0, w_ih1, w_hh, b_lstm, z, h1fin);
    k3_head<<<dim3(BATCH), dim3(128), 0, stream>>>(h1fin, mu_w, mu_b, lv_w, lv_b, out);
}

// Round 3
// 160.203 us; speedup vs baseline: 3.5524x; 3.4147x over previous
//
#include <hip/hip_runtime.h>
#include <hip/hip_bf16.h>
#include <math.h>

#define BATCH 128
#define WIN   128      // WINDOW = time steps / conv groups
#define NF    128      // conv spatial length
#define KC    16
#define POOL  65
#define NFC1  32       // number of LSTMs
#define HS    32       // hidden size
#define LW    40       // LDS h-buffer row stride in bf16 elems (80B, breaks bank conflicts)

typedef float f32x4 __attribute__((ext_vector_type(4)));
typedef short bf16x8 __attribute__((ext_vector_type(8)));

__device__ __forceinline__ float sigf(float x) {
    return __builtin_amdgcn_rcpf(1.f + __expf(-x));
}
__device__ __forceinline__ float tanhf_fast(float x) {
    float m = __expf(2.f * x);
    return fmaf(-2.f, __builtin_amdgcn_rcpf(m + 1.f), 1.f);
}
__device__ __forceinline__ float cellf(float& c, float gi, float gf, float gg, float go) {
    float si = sigf(gi), sf = sigf(gf), tg = tanhf_fast(gg), so = sigf(go);
    c = fmaf(sf, c, si * tg);
    return so * tanhf_fast(c);
}
__device__ __forceinline__ unsigned short f2bf(float x) {
    __hip_bfloat16 h = __float2bfloat16(x);
    unsigned short u; __builtin_memcpy(&u, &h, 2); return u;
}
__device__ __forceinline__ bf16x8 load_row8_bf16(const float* row) {
    float4 lo = ((const float4*)row)[0];
    float4 hi = ((const float4*)row)[1];
    union { bf16x8 v; unsigned short u[8]; } t;
    t.u[0] = f2bf(lo.x); t.u[1] = f2bf(lo.y); t.u[2] = f2bf(lo.z); t.u[3] = f2bf(lo.w);
    t.u[4] = f2bf(hi.x); t.u[5] = f2bf(hi.y); t.u[6] = f2bf(hi.z); t.u[7] = f2bf(hi.w);
    return t.v;
}

// ---------------- K1: grouped conv1d + relu + maxpool(2,2,pad1) + fc1 ----------------
// grid = WIN*16 blocks; block handles (w, 8 batches); 256 threads.
// z output layout: [t=w][f=o][b]
__global__ __launch_bounds__(256) void k1_conv_fc1(
    const float* __restrict__ x, const float* __restrict__ conv_w, const float* __restrict__ conv_b,
    const float* __restrict__ fc1_w, const float* __restrict__ fc1_b, float* __restrict__ z)
{
    __shared__ float xp[8][NF + 2];          // zero-padded input rows
    __shared__ float pool[8][KC * POOL];     // 8 x 1040
    __shared__ float cw[KC][3];
    __shared__ float cb[KC];

    const int w = blockIdx.x >> 4;
    const int bbase = (blockIdx.x & 15) * 8;
    const int tid = threadIdx.x;

    if (tid < KC * 3) cw[tid / 3][tid % 3] = conv_w[(w * KC + tid / 3) * 3 + tid % 3];
    if (tid < KC) cb[tid] = conv_b[w * KC + tid];

    for (int i = tid; i < 8 * (NF + 2); i += 256) {
        int b = i / (NF + 2), p = i % (NF + 2);
        float v = 0.f;
        if (p >= 1 && p <= NF) v = x[(size_t)(bbase + b) * WIN * NF + (size_t)w * NF + (p - 1)];
        xp[b][p] = v;
    }
    __syncthreads();

    for (int i = tid; i < 8 * KC * POOL; i += 256) {
        int b = i / (KC * POOL);
        int r = i % (KC * POOL);
        int k = r / POOL, j = r % POOL;
        float w0 = cw[k][0], w1 = cw[k][1], w2 = cw[k][2], bb = cb[k];
        int p0 = 2 * j - 1, p1 = 2 * j;
        float m = 0.f;  // relu floor
        if (p0 >= 0) {
            float v = bb + w0 * xp[b][p0] + w1 * xp[b][p0 + 1] + w2 * xp[b][p0 + 2];
            m = fmaxf(m, v);
        }
        if (p1 <= NF - 1) {
            float v = bb + w0 * xp[b][p1] + w1 * xp[b][p1 + 1] + w2 * xp[b][p1 + 2];
            m = fmaxf(m, v);
        }
        pool[b][k * POOL + j] = m;
    }
    __syncthreads();

    // fc1: o = tid>>3 (lanes share w-rows 8-way), b = tid&7
    const int b = tid & 7, o = tid >> 3;
    const float4* w4 = (const float4*)(fc1_w + (size_t)o * (KC * POOL));
    const float4* p4 = (const float4*)(&pool[b][0]);
    float acc = fc1_b[o];
    #pragma unroll 4
    for (int i = 0; i < (KC * POOL) / 4; ++i) {
        float4 wv = w4[i], pv = p4[i];
        acc = fmaf(wv.x, pv.x, acc);
        acc = fmaf(wv.y, pv.y, acc);
        acc = fmaf(wv.z, pv.z, acc);
        acc = fmaf(wv.w, pv.w, acc);
    }
    z[(size_t)w * NFC1 * BATCH + (size_t)o * BATCH + (bbase + b)] = acc;
}

// ---------------- K2: 2-layer LSTM via bf16 MFMA, layer-pipelined ----------------
// grid = 32 f * 8 batch-tiles = 256 blocks of 256 threads (4 waves).
// waves 0,1 = layer0 (s=0,1 gate halves); waves 2,3 = layer1, one step behind.
// mfma_f32_16x16x32_bf16: M=16 batches, K=32 hidden, N-tiles of 16 gates.
// Cell is lane-local: gates i/f/g/o for (b,h) sit in n-tiles {s,2+s,4+s,6+s}
// at the same lane/reg (C-layout: col=lane&15, row=(lane>>4)*4+reg).
__global__ __launch_bounds__(256, 1) void k2_lstm_mfma(
    const float* __restrict__ w_ih0, const float* __restrict__ w_ih1,
    const float* __restrict__ w_hh, const float* __restrict__ b_lstm,
    const float* __restrict__ z, float* __restrict__ h1fin)
{
    __shared__ float zs[WIN][16];
    __shared__ __align__(16) unsigned short h0buf[16 * LW];
    __shared__ __align__(16) unsigned short h1buf[16 * LW];

    const int f = blockIdx.x >> 3;
    const int bbase = (blockIdx.x & 7) * 16;
    const int tid = threadIdx.x;
    const int wid = tid >> 6, lane = tid & 63;
    const bool isL0 = (wid < 2);
    const int s = wid & 1;
    const int col = lane & 15;       // A-row (batch) for frag reads; C-col (gate within tile)
    const int kg = lane >> 4;        // k-group; C-row group = kg*4+j

    // stage z for this (f, 16-batch) tile
    for (int i = tid; i < WIN * 16; i += 256) {
        int t = i >> 4, c = i & 15;
        zs[t][c] = z[(size_t)t * (NFC1 * BATCH) + f * BATCH + bbase + c];
    }
    for (int i = tid; i < 16 * LW; i += 256) { h0buf[i] = 0; h1buf[i] = 0; }

    // weight fragments (B-operand: lane holds W[g = nt*16+col][k = kg*8 .. +7])
    const float* WA = isL0 ? (w_hh + (size_t)f * 4096)          // layer0 hh
                           : (w_ih1 + (size_t)f * 4096);        // layer1 ih
    const float* WV = w_hh + (size_t)(NFC1 + f) * 4096;         // layer1 hh
    bf16x8 fA[4], fB[4];
    float bias[4], wi0[4];
    const int loff = isL0 ? 0 : (NFC1 * 128);
    #pragma unroll
    for (int gi = 0; gi < 4; ++gi) {
        int nt = gi * 2 + s;                 // gi: 0=i,1=f,2=g,3=o gate block
        int g = nt * 16 + col;
        fA[gi] = load_row8_bf16(WA + g * 32 + kg * 8);
        if (!isL0) fB[gi] = load_row8_bf16(WV + g * 32 + kg * 8);
        bias[gi] = b_lstm[loff + f * 128 + g];
        wi0[gi] = w_ih0[f * 128 + g];
    }
    __syncthreads();

    const int hread = col * LW + kg * 8;     // bf16x8 A-frag read offset (16B aligned: 80B rows)
    float cst[4] = {0.f, 0.f, 0.f, 0.f};
    float hout[4] = {0.f, 0.f, 0.f, 0.f};

    #pragma unroll 1
    for (int it = 0; it <= WIN; ++it) {
        const bool doL0 = isL0 && (it < WIN);
        const bool doL1 = (!isL0) && (it >= 1);
        bf16x8 hA = {}, hB = {};
        f32x4 zv = {};
        if (doL0) {
            hA = *(const bf16x8*)&h0buf[hread];
            zv = *(const f32x4*)&zs[it][kg * 4];
        }
        if (doL1) {
            hA = *(const bf16x8*)&h0buf[hread];
            hB = *(const bf16x8*)&h1buf[hread];
        }
        __syncthreads();   // all reads of h-buffers complete before overwrite

        if (doL0) {
            f32x4 aI, aF, aG, aO;
            #pragma unroll
            for (int j = 0; j < 4; ++j) {
                aI[j] = fmaf(zv[j], wi0[0], bias[0]);
                aF[j] = fmaf(zv[j], wi0[1], bias[1]);
                aG[j] = fmaf(zv[j], wi0[2], bias[2]);
                aO[j] = fmaf(zv[j], wi0[3], bias[3]);
            }
            aI = __builtin_amdgcn_mfma_f32_16x16x32_bf16(hA, fA[0], aI, 0, 0, 0);
            aF = __builtin_amdgcn_mfma_f32_16x16x32_bf16(hA, fA[1], aF, 0, 0, 0);
            aG = __builtin_amdgcn_mfma_f32_16x16x32_bf16(hA, fA[2], aG, 0, 0, 0);
            aO = __builtin_amdgcn_mfma_f32_16x16x32_bf16(hA, fA[3], aO, 0, 0, 0);
            #pragma unroll
            for (int j = 0; j < 4; ++j)
                hout[j] = cellf(cst[j], aI[j], aF[j], aG[j], aO[j]);
        }
        if (doL1) {
            f32x4 aI, aF, aG, aO;
            #pragma unroll
            for (int j = 0; j < 4; ++j) { aI[j] = bias[0]; aF[j] = bias[1]; aG[j] = bias[2]; aO[j] = bias[3]; }
            aI = __builtin_amdgcn_mfma_f32_16x16x32_bf16(hA, fA[0], aI, 0, 0, 0);
            aI = __builtin_amdgcn_mfma_f32_16x16x32_bf16(hB, fB[0], aI, 0, 0, 0);
            aF = __builtin_amdgcn_mfma_f32_16x16x32_bf16(hA, fA[1], aF, 0, 0, 0);
            aF = __builtin_amdgcn_mfma_f32_16x16x32_bf16(hB, fB[1], aF, 0, 0, 0);
            aG = __builtin_amdgcn_mfma_f32_16x16x32_bf16(hA, fA[2], aG, 0, 0, 0);
            aG = __builtin_amdgcn_mfma_f32_16x16x32_bf16(hB, fB[2], aG, 0, 0, 0);
            aO = __builtin_amdgcn_mfma_f32_16x16x32_bf16(hA, fA[3], aO, 0, 0, 0);
            aO = __builtin_amdgcn_mfma_f32_16x16x32_bf16(hB, fB[3], aO, 0, 0, 0);
            #pragma unroll
            for (int j = 0; j < 4; ++j)
                hout[j] = cellf(cst[j], aI[j], aF[j], aG[j], aO[j]);
            if (it == WIN) {
                #pragma unroll
                for (int j = 0; j < 4; ++j)
                    h1fin[(size_t)(bbase + kg * 4 + j) * (NFC1 * HS) + f * HS + 16 * s + col] = hout[j];
            }
        }

        if (doL0) {
            #pragma unroll
            for (int j = 0; j < 4; ++j)
                h0buf[(kg * 4 + j) * LW + 16 * s + col] = f2bf(hout[j]);
        }
        if (doL1 && it < WIN) {
            #pragma unroll
            for (int j = 0; j < 4; ++j)
                h1buf[(kg * 4 + j) * LW + 16 * s + col] = f2bf(hout[j]);
        }
        __syncthreads();   // writes visible before next iteration's reads
    }
}

// ---------------- K3: head (mu / logvar / CI bounds) ----------------
__global__ __launch_bounds__(128) void k3_head(
    const float* __restrict__ h1fin, const float* __restrict__ mu_w, const float* __restrict__ mu_b,
    const float* __restrict__ lv_w, const float* __restrict__ lv_b, float* __restrict__ out)
{
    const int b = blockIdx.x, tid = threadIdx.x;
    const float* hrow = h1fin + (size_t)b * (NFC1 * HS);
    float am = 0.f, al = 0.f;
    for (int i = tid; i < NFC1 * HS; i += 128) {
        float h = hrow[i];
        am = fmaf(h, mu_w[i], am);
        al = fmaf(h, lv_w[i], al);
    }
    for (int off = 32; off >= 1; off >>= 1) {
        am += __shfl_down(am, off, 64);
        al += __shfl_down(al, off, 64);
    }
    __shared__ float sm[2], sl[2];
    const int wv = tid >> 6, ln = tid & 63;
    if (ln == 0) { sm[wv] = am; sl[wv] = al; }
    __syncthreads();
    if (tid == 0) {
        float mu = sm[0] + sm[1] + mu_b[0];
        float lv = sl[0] + sl[1] + lv_b[0];
        float sg = expf(0.5f * lv);
        out[b]           = mu - 1.96f * sg;
        out[128 + b]     = mu;
        out[256 + b]     = mu + 1.96f * sg;
        out[384 + b]     = lv;
    }
}

extern "C" void kernel_launch(void* const* d_in, const int* in_sizes, int n_in,
                              void* d_out, int out_size, void* d_ws, size_t ws_size,
                              hipStream_t stream)
{
    const float* x      = (const float*)d_in[0];
    const float* conv_w = (const float*)d_in[1];
    const float* conv_b = (const float*)d_in[2];
    const float* fc1_w  = (const float*)d_in[3];
    const float* fc1_b  = (const float*)d_in[4];
    const float* w_ih0  = (const float*)d_in[5];
    const float* w_ih1  = (const float*)d_in[6];
    const float* w_hh   = (const float*)d_in[7];
    const float* b_lstm = (const float*)d_in[8];
    const float* mu_w   = (const float*)d_in[9];
    const float* mu_b   = (const float*)d_in[10];
    const float* lv_w   = (const float*)d_in[11];
    const float* lv_b   = (const float*)d_in[12];
    float* out = (float*)d_out;

    float* z     = (float*)d_ws;                         // WIN*NFC1*BATCH floats (2 MB)
    float* h1fin = z + (size_t)WIN * NFC1 * BATCH;       // BATCH*NFC1*HS floats (0.5 MB)

    k1_conv_fc1<<<dim3(WIN * 16), dim3(256), 0, stream>>>(x, conv_w, conv_b, fc1_w, fc1_b, z);
    k2_lstm_mfma<<<dim3(NFC1 * 8), dim3(256), 0, stream>>>(w_ih0, w_ih1, w_hh, b_lstm, z, h1fin);
    k3_head<<<dim3(BATCH), dim3(128), 0, stream>>>(h1fin, mu_w, mu_b, lv_w, lv_b, out);
}

// Round 4
// 135.363 us; speedup vs baseline: 4.2043x; 1.1835x over previous
//
#include <hip/hip_runtime.h>
#include <hip/hip_bf16.h>
#include <math.h>

#define BATCH 128
#define WIN   128      // time steps / conv groups
#define NF    128      // conv spatial length
#define KC    16
#define POOL  65
#define NFC1  32       // number of LSTMs
#define HS    32       // hidden size
#define LW    40       // k2 h-buffer row stride (bf16 elems, 80B)
#define KP    1056     // fc1 K padded to multiple of 32
#define PSTR  1064     // poolb row stride (bf16 elems; 2128B -> conflict-free b128 reads)

typedef float f32x4 __attribute__((ext_vector_type(4)));
typedef short bf16x8 __attribute__((ext_vector_type(8)));

__device__ __forceinline__ float sigf(float x) {
    return __builtin_amdgcn_rcpf(1.f + __expf(-x));
}
__device__ __forceinline__ float tanhf_fast(float x) {
    float m = __expf(2.f * x);
    return fmaf(-2.f, __builtin_amdgcn_rcpf(m + 1.f), 1.f);
}
__device__ __forceinline__ float cellf(float& c, float gi, float gf, float gg, float go) {
    float si = sigf(gi), sf = sigf(gf), tg = tanhf_fast(gg), so = sigf(go);
    c = fmaf(sf, c, si * tg);
    return so * tanhf_fast(c);
}
__device__ __forceinline__ unsigned short f2bf(float x) {
    __hip_bfloat16 h = __float2bfloat16(x);
    unsigned short u; __builtin_memcpy(&u, &h, 2); return u;
}
__device__ __forceinline__ float bf2f(unsigned short u) {
    unsigned int v = ((unsigned int)u) << 16;
    float f; __builtin_memcpy(&f, &v, 4); return f;
}
__device__ __forceinline__ bf16x8 load_row8_bf16(const float* row) {
    float4 lo = ((const float4*)row)[0];
    float4 hi = ((const float4*)row)[1];
    union { bf16x8 v; unsigned short u[8]; } t;
    t.u[0] = f2bf(lo.x); t.u[1] = f2bf(lo.y); t.u[2] = f2bf(lo.z); t.u[3] = f2bf(lo.w);
    t.u[4] = f2bf(hi.x); t.u[5] = f2bf(hi.y); t.u[6] = f2bf(hi.z); t.u[7] = f2bf(hi.w);
    return t.v;
}

// ---------------- K0: convert fc1_w -> bf16, K-padded [32][KP] ----------------
__global__ __launch_bounds__(256) void k0_wconv(
    const float* __restrict__ fc1_w, unsigned short* __restrict__ w_bf)
{
    const int o = blockIdx.x;
    for (int i = threadIdx.x; i < KP; i += 256) {
        float v = (i < KC * POOL) ? fc1_w[(size_t)o * (KC * POOL) + i] : 0.f;
        w_bf[(size_t)o * KP + i] = f2bf(v);
    }
}

// ---------------- K1: grouped conv1d + relu + maxpool + fc1 (MFMA) ----------------
// grid = 128 w * 8 batch-tiles(16) = 1024 blocks of 128 threads (2 waves).
// conv/pool -> bf16 LDS tile [16 b][1040 k]; fc1 = MFMA M=16 batches, N=32 o, K=1056.
__global__ __launch_bounds__(128, 2) void k1_conv_fc1(
    const float* __restrict__ x, const float* __restrict__ conv_w, const float* __restrict__ conv_b,
    const unsigned short* __restrict__ w_bf, const float* __restrict__ fc1_b, float* __restrict__ z)
{
    __shared__ __align__(16) unsigned short xp[16][132];     // bf16, xp[b][i] = x[i-1], 0-padded
    __shared__ __align__(16) unsigned short poolb[16 * PSTR];
    __shared__ float cw[KC][3];
    __shared__ float cb[KC];
    __shared__ float fb[NFC1];

    const int w = blockIdx.x >> 3;
    const int bbase = (blockIdx.x & 7) * 16;
    const int tid = threadIdx.x;

    if (tid < KC * 3) cw[tid / 3][tid % 3] = conv_w[(w * KC + tid / 3) * 3 + tid % 3];
    if (tid >= 64 && tid < 64 + KC) cb[tid - 64] = conv_b[w * KC + (tid - 64)];
    if (tid >= 96 && tid < 96 + NFC1) fb[tid - 96] = fc1_b[tid - 96];

    for (int i = tid; i < 16 * 132; i += 128) {
        int b = i / 132, p = i % 132;
        float v = (p >= 1 && p <= NF) ? x[(size_t)(bbase + b) * (WIN * NF) + (size_t)w * NF + (p - 1)] : 0.f;
        xp[b][p] = f2bf(v);
    }
    __syncthreads();

    // conv + relu + pool: thread -> (b0, k) and (b0+8, k); sliding window over xp
    {
        const int b0 = tid >> 4;       // 0..7
        const int k = tid & 15;
        const float w0 = cw[k][0], w1 = cw[k][1], w2 = cw[k][2], bb = cb[k];
        #pragma unroll
        for (int half = 0; half < 2; ++half) {
            const int b = b0 + half * 8;
            // window: v0=xp[2j-1], v1=xp[2j], v2=xp[2j+1], v3=xp[2j+2]
            float v1 = 0.f;
            float v2 = bf2f(xp[b][0]);
            float v3 = bf2f(xp[b][1]);
            unsigned short* prow = &poolb[b * PSTR + k * POOL];
            #pragma unroll 1
            for (int j = 0; j < POOL; ++j) {
                float v0 = v1; v1 = v2; v2 = v3;
                v3 = bf2f(xp[b][2 * j + 2]);
                float oa = bb + w0 * v0 + w1 * v1 + w2 * v2;   // out(2j-1)
                float ob = bb + w0 * v1 + w1 * v2 + w2 * v3;   // out(2j)
                float m = 0.f;                                  // relu floor
                if (j > 0)        m = fmaxf(m, oa);
                if (j < POOL - 1) m = fmaxf(m, ob);
                prow[j] = f2bf(m);
            }
        }
    }
    // zero K-pad tail (cols 1040..1055)
    for (int i = tid; i < 16 * (KP - KC * POOL); i += 128) {
        int b = i >> 4, c = i & 15;
        poolb[b * PSTR + KC * POOL + c] = 0;
    }
    __syncthreads();

    // fc1 MFMA: wave wid -> ntile = wid (o = wid*16+col)
    const int lane = tid & 63;
    const int wid = tid >> 6;
    const int col = lane & 15;
    const int kg = lane >> 4;
    const int g = wid * 16 + col;
    f32x4 acc;
    {
        float bias = fb[g];
        acc[0] = bias; acc[1] = bias; acc[2] = bias; acc[3] = bias;
    }
    const unsigned short* wrow = w_bf + (size_t)g * KP;
    #pragma unroll 4
    for (int ks = 0; ks < KP / 32; ++ks) {
        bf16x8 aP = *(const bf16x8*)&poolb[col * PSTR + ks * 32 + kg * 8];
        bf16x8 bW = *(const bf16x8*)&wrow[ks * 32 + kg * 8];
        acc = __builtin_amdgcn_mfma_f32_16x16x32_bf16(aP, bW, acc, 0, 0, 0);
    }
    // D: row(kg*4+j)=batch, col=o -> batches consecutive: float4 store
    float4 st; st.x = acc[0]; st.y = acc[1]; st.z = acc[2]; st.w = acc[3];
    *(float4*)&z[(size_t)w * (NFC1 * BATCH) + (size_t)g * BATCH + bbase + kg * 4] = st;
}

// ---------------- K2: 2-layer LSTM via bf16 MFMA, layer-pipelined ----------------
// grid = 32 f * 16 batch-tiles(8) = 512 blocks of 256 threads (4 waves) -> 2 blocks/CU.
// waves 0,1 = layer0 (s halves); waves 2,3 = layer1 one step behind.
// Double-buffered h (parity) -> single barrier per step.
__global__ __launch_bounds__(256, 2) void k2_lstm_mfma(
    const float* __restrict__ w_ih0, const float* __restrict__ w_ih1,
    const float* __restrict__ w_hh, const float* __restrict__ b_lstm,
    const float* __restrict__ z, float* __restrict__ h1fin)
{
    __shared__ float zs[WIN][16];
    __shared__ __align__(16) unsigned short h0b[2][16 * LW];
    __shared__ __align__(16) unsigned short h1b[2][16 * LW];

    const int f = blockIdx.x >> 4;
    const int bbase = (blockIdx.x & 15) * 8;
    const int tid = threadIdx.x;
    const int wid = tid >> 6, lane = tid & 63;
    const bool isL0 = (wid < 2);
    const int s = wid & 1;
    const int col = lane & 15;
    const int kg = lane >> 4;

    for (int i = tid; i < WIN * 16; i += 256) {
        int t = i >> 4, c = i & 15;
        zs[t][c] = (c < 8) ? z[(size_t)t * (NFC1 * BATCH) + f * BATCH + bbase + c] : 0.f;
    }
    for (int i = tid; i < 2 * 16 * LW; i += 256) { h0b[0][i] = 0; h1b[0][i] = 0; }

    const float* WA = isL0 ? (w_hh + (size_t)f * 4096)
                           : (w_ih1 + (size_t)f * 4096);
    const float* WV = w_hh + (size_t)(NFC1 + f) * 4096;
    bf16x8 fA[4], fB[4];
    float bias[4], wi0[4];
    const int loff = isL0 ? 0 : (NFC1 * 128);
    #pragma unroll
    for (int gi = 0; gi < 4; ++gi) {
        int nt = gi * 2 + s;
        int g = nt * 16 + col;
        fA[gi] = load_row8_bf16(WA + g * 32 + kg * 8);
        if (!isL0) fB[gi] = load_row8_bf16(WV + g * 32 + kg * 8);
        bias[gi] = b_lstm[loff + f * 128 + g];
        wi0[gi] = w_ih0[f * 128 + g];
    }
    __syncthreads();

    const int hread = col * LW + kg * 8;
    float cst[4] = {0.f, 0.f, 0.f, 0.f};
    int p = 0;

    #pragma unroll 1
    for (int it = 0; it <= WIN; ++it) {
        const bool doL0 = isL0 && (it < WIN);
        const bool doL1 = (!isL0) && (it >= 1);

        if (doL0) {
            bf16x8 hA = *(const bf16x8*)&h0b[p][hread];
            f32x4 zv = *(const f32x4*)&zs[it][kg * 4];
            f32x4 aI, aF, aG, aO;
            #pragma unroll
            for (int j = 0; j < 4; ++j) {
                aI[j] = fmaf(zv[j], wi0[0], bias[0]);
                aF[j] = fmaf(zv[j], wi0[1], bias[1]);
                aG[j] = fmaf(zv[j], wi0[2], bias[2]);
                aO[j] = fmaf(zv[j], wi0[3], bias[3]);
            }
            aI = __builtin_amdgcn_mfma_f32_16x16x32_bf16(hA, fA[0], aI, 0, 0, 0);
            aF = __builtin_amdgcn_mfma_f32_16x16x32_bf16(hA, fA[1], aF, 0, 0, 0);
            aG = __builtin_amdgcn_mfma_f32_16x16x32_bf16(hA, fA[2], aG, 0, 0, 0);
            aO = __builtin_amdgcn_mfma_f32_16x16x32_bf16(hA, fA[3], aO, 0, 0, 0);
            #pragma unroll
            for (int j = 0; j < 4; ++j) {
                float h = cellf(cst[j], aI[j], aF[j], aG[j], aO[j]);
                h0b[p ^ 1][(kg * 4 + j) * LW + 16 * s + col] = f2bf(h);
            }
        }
        if (doL1) {
            bf16x8 hA = *(const bf16x8*)&h0b[p][hread];
            bf16x8 hB = *(const bf16x8*)&h1b[p][hread];
            f32x4 aI, aF, aG, aO;
            #pragma unroll
            for (int j = 0; j < 4; ++j) { aI[j] = bias[0]; aF[j] = bias[1]; aG[j] = bias[2]; aO[j] = bias[3]; }
            aI = __builtin_amdgcn_mfma_f32_16x16x32_bf16(hA, fA[0], aI, 0, 0, 0);
            aI = __builtin_amdgcn_mfma_f32_16x16x32_bf16(hB, fB[0], aI, 0, 0, 0);
            aF = __builtin_amdgcn_mfma_f32_16x16x32_bf16(hA, fA[1], aF, 0, 0, 0);
            aF = __builtin_amdgcn_mfma_f32_16x16x32_bf16(hB, fB[1], aF, 0, 0, 0);
            aG = __builtin_amdgcn_mfma_f32_16x16x32_bf16(hA, fA[2], aG, 0, 0, 0);
            aG = __builtin_amdgcn_mfma_f32_16x16x32_bf16(hB, fB[2], aG, 0, 0, 0);
            aO = __builtin_amdgcn_mfma_f32_16x16x32_bf16(hA, fA[3], aO, 0, 0, 0);
            aO = __builtin_amdgcn_mfma_f32_16x16x32_bf16(hB, fB[3], aO, 0, 0, 0);
            if (it < WIN) {
                #pragma unroll
                for (int j = 0; j < 4; ++j) {
                    float h = cellf(cst[j], aI[j], aF[j], aG[j], aO[j]);
                    h1b[p ^ 1][(kg * 4 + j) * LW + 16 * s + col] = f2bf(h);
                }
            } else {
                #pragma unroll
                for (int j = 0; j < 4; ++j) {
                    float h = cellf(cst[j], aI[j], aF[j], aG[j], aO[j]);
                    if (kg < 2)
                        h1fin[(size_t)(bbase + kg * 4 + j) * (NFC1 * HS) + f * HS + 16 * s + col] = h;
                }
            }
        }
        __syncthreads();
        p ^= 1;
    }
}

// ---------------- K3: head (mu / logvar / CI bounds) ----------------
__global__ __launch_bounds__(128) void k3_head(
    const float* __restrict__ h1fin, const float* __restrict__ mu_w, const float* __restrict__ mu_b,
    const float* __restrict__ lv_w, const float* __restrict__ lv_b, float* __restrict__ out)
{
    const int b = blockIdx.x, tid = threadIdx.x;
    const float* hrow = h1fin + (size_t)b * (NFC1 * HS);
    float am = 0.f, al = 0.f;
    for (int i = tid; i < NFC1 * HS; i += 128) {
        float h = hrow[i];
        am = fmaf(h, mu_w[i], am);
        al = fmaf(h, lv_w[i], al);
    }
    for (int off = 32; off >= 1; off >>= 1) {
        am += __shfl_down(am, off, 64);
        al += __shfl_down(al, off, 64);
    }
    __shared__ float sm[2], sl[2];
    const int wv = tid >> 6, ln = tid & 63;
    if (ln == 0) { sm[wv] = am; sl[wv] = al; }
    __syncthreads();
    if (tid == 0) {
        float mu = sm[0] + sm[1] + mu_b[0];
        float lv = sl[0] + sl[1] + lv_b[0];
        float sg = expf(0.5f * lv);
        out[b]           = mu - 1.96f * sg;
        out[128 + b]     = mu;
        out[256 + b]     = mu + 1.96f * sg;
        out[384 + b]     = lv;
    }
}

extern "C" void kernel_launch(void* const* d_in, const int* in_sizes, int n_in,
                              void* d_out, int out_size, void* d_ws, size_t ws_size,
                              hipStream_t stream)
{
    const float* x      = (const float*)d_in[0];
    const float* conv_w = (const float*)d_in[1];
    const float* conv_b = (const float*)d_in[2];
    const float* fc1_w  = (const float*)d_in[3];
    const float* fc1_b  = (const float*)d_in[4];
    const float* w_ih0  = (const float*)d_in[5];
    const float* w_ih1  = (const float*)d_in[6];
    const float* w_hh   = (const float*)d_in[7];
    const float* b_lstm = (const float*)d_in[8];
    const float* mu_w   = (const float*)d_in[9];
    const float* mu_b   = (const float*)d_in[10];
    const float* lv_w   = (const float*)d_in[11];
    const float* lv_b   = (const float*)d_in[12];
    float* out = (float*)d_out;

    float* z     = (float*)d_ws;                              // 524288 floats
    float* h1fin = z + (size_t)WIN * NFC1 * BATCH;            // 131072 floats
    unsigned short* w_bf = (unsigned short*)(h1fin + (size_t)BATCH * NFC1 * HS);  // 32*KP bf16

    k0_wconv<<<dim3(NFC1), dim3(256), 0, stream>>>(fc1_w, w_bf);
    k1_conv_fc1<<<dim3(WIN * 8), dim3(128), 0, stream>>>(x, conv_w, conv_b, w_bf, fc1_b, z);
    k2_lstm_mfma<<<dim3(NFC1 * 16), dim3(256), 0, stream>>>(w_ih0, w_ih1, w_hh, b_lstm, z, h1fin);
    k3_head<<<dim3(BATCH), dim3(128), 0, stream>>>(h1fin, mu_w, mu_b, lv_w, lv_b, out);
}

// Round 5
// 100.400 us; speedup vs baseline: 5.6684x; 1.3482x over previous
//
#include <hip/hip_runtime.h>
#include <hip/hip_bf16.h>
#include <math.h>

#define BATCH 128
#define WIN   128      // time steps / conv groups
#define NF    128      // conv spatial length
#define KC    16
#define POOL  65
#define NFC1  32       // number of LSTMs
#define HS    32       // hidden size
#define LW    40       // k2 h-buffer row stride (bf16 elems, 80B)
#define KP    1056     // fc1 K padded to multiple of 32
#define PSTR  1064     // poolb row stride (bf16 elems; 2128B -> conflict-free b128 reads)

typedef float f32x4 __attribute__((ext_vector_type(4)));
typedef short bf16x8 __attribute__((ext_vector_type(8)));

// fused LSTM cell: sig(i)*tanh(g) and sig(o)*tanh(c) share one rcp each.
// 5 exp + 3 rcp (was 5 exp + 5 rcp). c clamped to +-30 before exp(2c) so
// exp never overflows (inf*rcp(inf) = NaN hazard).
__device__ __forceinline__ float cellf(float& c, float gi, float gf, float gg, float go) {
    float ei = __expf(-gi);            // e^-i
    float eg = __expf(2.f * gg);       // e^{2g}
    float ef = __expf(-gf);            // e^-f
    float sf = __builtin_amdgcn_rcpf(1.f + ef);
    float num = eg - 1.f;
    float den = (1.f + ei) * (eg + 1.f);
    c = fmaf(sf, c, num * __builtin_amdgcn_rcpf(den));
    float cc = fminf(fmaxf(c, -30.f), 30.f);
    float eo = __expf(-go);
    float ec = __expf(2.f * cc);
    return (ec - 1.f) * __builtin_amdgcn_rcpf((1.f + eo) * (ec + 1.f));
}
__device__ __forceinline__ unsigned short f2bf(float x) {
    __hip_bfloat16 h = __float2bfloat16(x);
    unsigned short u; __builtin_memcpy(&u, &h, 2); return u;
}
__device__ __forceinline__ float bf2f(unsigned short u) {
    unsigned int v = ((unsigned int)u) << 16;
    float f; __builtin_memcpy(&f, &v, 4); return f;
}
__device__ __forceinline__ bf16x8 load_row8_bf16(const float* row) {
    float4 lo = ((const float4*)row)[0];
    float4 hi = ((const float4*)row)[1];
    union { bf16x8 v; unsigned short u[8]; } t;
    t.u[0] = f2bf(lo.x); t.u[1] = f2bf(lo.y); t.u[2] = f2bf(lo.z); t.u[3] = f2bf(lo.w);
    t.u[4] = f2bf(hi.x); t.u[5] = f2bf(hi.y); t.u[6] = f2bf(hi.z); t.u[7] = f2bf(hi.w);
    return t.v;
}

// ---------------- K0: convert fc1_w -> bf16, K-padded [32][KP] ----------------
__global__ __launch_bounds__(256) void k0_wconv(
    const float* __restrict__ fc1_w, unsigned short* __restrict__ w_bf)
{
    const int o = blockIdx.x;
    for (int i = threadIdx.x; i < KP; i += 256) {
        float v = (i < KC * POOL) ? fc1_w[(size_t)o * (KC * POOL) + i] : 0.f;
        w_bf[(size_t)o * KP + i] = f2bf(v);
    }
}

// ---------------- K1: grouped conv1d + relu + maxpool + fc1 (MFMA) ----------------
// grid = 128 w * 8 batch-tiles(16) = 1024 blocks of 128 threads (2 waves).
__global__ __launch_bounds__(128, 2) void k1_conv_fc1(
    const float* __restrict__ x, const float* __restrict__ conv_w, const float* __restrict__ conv_b,
    const unsigned short* __restrict__ w_bf, const float* __restrict__ fc1_b, float* __restrict__ z)
{
    __shared__ __align__(16) unsigned short xp[16][132];     // bf16, xp[b][i] = x[i-1], 0-padded
    __shared__ __align__(16) unsigned short poolb[16 * PSTR];
    __shared__ float cw[KC][3];
    __shared__ float cb[KC];
    __shared__ float fb[NFC1];

    const int w = blockIdx.x >> 3;
    const int bbase = (blockIdx.x & 7) * 16;
    const int tid = threadIdx.x;

    if (tid < KC * 3) cw[tid / 3][tid % 3] = conv_w[(w * KC + tid / 3) * 3 + tid % 3];
    if (tid >= 64 && tid < 64 + KC) cb[tid - 64] = conv_b[w * KC + (tid - 64)];
    if (tid >= 96 && tid < 96 + NFC1) fb[tid - 96] = fc1_b[tid - 96];

    for (int i = tid; i < 16 * 132; i += 128) {
        int b = i / 132, p = i % 132;
        float v = (p >= 1 && p <= NF) ? x[(size_t)(bbase + b) * (WIN * NF) + (size_t)w * NF + (p - 1)] : 0.f;
        xp[b][p] = f2bf(v);
    }
    __syncthreads();

    // conv + relu + pool: thread -> (b0, k) and (b0+8, k); sliding window over xp
    {
        const int b0 = tid >> 4;       // 0..7
        const int k = tid & 15;
        const float w0 = cw[k][0], w1 = cw[k][1], w2 = cw[k][2], bb = cb[k];
        #pragma unroll
        for (int half = 0; half < 2; ++half) {
            const int b = b0 + half * 8;
            float v1 = 0.f;
            float v2 = bf2f(xp[b][0]);
            float v3 = bf2f(xp[b][1]);
            unsigned short* prow = &poolb[b * PSTR + k * POOL];
            #pragma unroll 1
            for (int j = 0; j < POOL; ++j) {
                float v0 = v1; v1 = v2; v2 = v3;
                v3 = bf2f(xp[b][2 * j + 2]);
                float oa = bb + w0 * v0 + w1 * v1 + w2 * v2;   // out(2j-1)
                float ob = bb + w0 * v1 + w1 * v2 + w2 * v3;   // out(2j)
                float m = 0.f;                                  // relu floor
                if (j > 0)        m = fmaxf(m, oa);
                if (j < POOL - 1) m = fmaxf(m, ob);
                prow[j] = f2bf(m);
            }
        }
    }
    // zero K-pad tail (cols 1040..1055)
    for (int i = tid; i < 16 * (KP - KC * POOL); i += 128) {
        int b = i >> 4, c = i & 15;
        poolb[b * PSTR + KC * POOL + c] = 0;
    }
    __syncthreads();

    // fc1 MFMA: wave wid -> ntile = wid (o = wid*16+col)
    const int lane = tid & 63;
    const int wid = tid >> 6;
    const int col = lane & 15;
    const int kg = lane >> 4;
    const int g = wid * 16 + col;
    f32x4 acc;
    {
        float bias = fb[g];
        acc[0] = bias; acc[1] = bias; acc[2] = bias; acc[3] = bias;
    }
    const unsigned short* wrow = w_bf + (size_t)g * KP;
    #pragma unroll 4
    for (int ks = 0; ks < KP / 32; ++ks) {
        bf16x8 aP = *(const bf16x8*)&poolb[col * PSTR + ks * 32 + kg * 8];
        bf16x8 bW = *(const bf16x8*)&wrow[ks * 32 + kg * 8];
        acc = __builtin_amdgcn_mfma_f32_16x16x32_bf16(aP, bW, acc, 0, 0, 0);
    }
    float4 st; st.x = acc[0]; st.y = acc[1]; st.z = acc[2]; st.w = acc[3];
    *(float4*)&z[(size_t)w * (NFC1 * BATCH) + (size_t)g * BATCH + bbase + kg * 4] = st;
}

// ---------------- K2: 2-layer LSTM via bf16 MFMA, layer-pipelined ----------------
// grid = 32 f * 8 batch-tiles(16) = 256 blocks of 256 threads (4 waves).
// waves 0,1 = layer0 (s halves); waves 2,3 = layer1 one step behind.
// Parity double-buffered h -> single barrier per step.
__global__ __launch_bounds__(256, 1) void k2_lstm_mfma(
    const float* __restrict__ w_ih0, const float* __restrict__ w_ih1,
    const float* __restrict__ w_hh, const float* __restrict__ b_lstm,
    const float* __restrict__ z, float* __restrict__ h1fin)
{
    __shared__ float zs[WIN][16];
    __shared__ __align__(16) unsigned short h0b[2][16 * LW];
    __shared__ __align__(16) unsigned short h1b[2][16 * LW];

    const int f = blockIdx.x >> 3;
    const int bbase = (blockIdx.x & 7) * 16;
    const int tid = threadIdx.x;
    const int wid = tid >> 6, lane = tid & 63;
    const bool isL0 = (wid < 2);
    const int s = wid & 1;
    const int col = lane & 15;
    const int kg = lane >> 4;

    for (int i = tid; i < WIN * 16; i += 256) {
        int t = i >> 4, c = i & 15;
        zs[t][c] = z[(size_t)t * (NFC1 * BATCH) + f * BATCH + bbase + c];
    }
    for (int i = tid; i < 2 * 16 * LW; i += 256) { h0b[0][i] = 0; h1b[0][i] = 0; }

    const float* WA = isL0 ? (w_hh + (size_t)f * 4096)
                           : (w_ih1 + (size_t)f * 4096);
    const float* WV = w_hh + (size_t)(NFC1 + f) * 4096;
    bf16x8 fA[4], fB[4];
    float bias[4], wi0[4];
    const int loff = isL0 ? 0 : (NFC1 * 128);
    #pragma unroll
    for (int gi = 0; gi < 4; ++gi) {
        int nt = gi * 2 + s;
        int g = nt * 16 + col;
        fA[gi] = load_row8_bf16(WA + g * 32 + kg * 8);
        if (!isL0) fB[gi] = load_row8_bf16(WV + g * 32 + kg * 8);
        bias[gi] = b_lstm[loff + f * 128 + g];
        wi0[gi] = w_ih0[f * 128 + g];
    }
    __syncthreads();

    const int hread = col * LW + kg * 8;
    float cst[4] = {0.f, 0.f, 0.f, 0.f};
    int p = 0;
    f32x4 zv = *(const f32x4*)&zs[0][kg * 4];   // prefetched z for current step

    #pragma unroll 1
    for (int it = 0; it <= WIN; ++it) {
        const bool doL0 = isL0 && (it < WIN);
        const bool doL1 = (!isL0) && (it >= 1);

        if (doL0) {
            bf16x8 hA = *(const bf16x8*)&h0b[p][hread];
            f32x4 aI, aF, aG, aO;
            #pragma unroll
            for (int j = 0; j < 4; ++j) {
                aI[j] = fmaf(zv[j], wi0[0], bias[0]);
                aF[j] = fmaf(zv[j], wi0[1], bias[1]);
                aG[j] = fmaf(zv[j], wi0[2], bias[2]);
                aO[j] = fmaf(zv[j], wi0[3], bias[3]);
            }
            aI = __builtin_amdgcn_mfma_f32_16x16x32_bf16(hA, fA[0], aI, 0, 0, 0);
            aF = __builtin_amdgcn_mfma_f32_16x16x32_bf16(hA, fA[1], aF, 0, 0, 0);
            aG = __builtin_amdgcn_mfma_f32_16x16x32_bf16(hA, fA[2], aG, 0, 0, 0);
            aO = __builtin_amdgcn_mfma_f32_16x16x32_bf16(hA, fA[3], aO, 0, 0, 0);
            // prefetch next step's z while MFMAs are in flight
            if (it + 1 < WIN) zv = *(const f32x4*)&zs[it + 1][kg * 4];
            #pragma unroll
            for (int j = 0; j < 4; ++j) {
                float h = cellf(cst[j], aI[j], aF[j], aG[j], aO[j]);
                h0b[p ^ 1][(kg * 4 + j) * LW + 16 * s + col] = f2bf(h);
            }
        }
        if (doL1) {
            bf16x8 hA = *(const bf16x8*)&h0b[p][hread];
            bf16x8 hB = *(const bf16x8*)&h1b[p][hread];
            f32x4 aI, aF, aG, aO;
            #pragma unroll
            for (int j = 0; j < 4; ++j) { aI[j] = bias[0]; aF[j] = bias[1]; aG[j] = bias[2]; aO[j] = bias[3]; }
            aI = __builtin_amdgcn_mfma_f32_16x16x32_bf16(hA, fA[0], aI, 0, 0, 0);
            aI = __builtin_amdgcn_mfma_f32_16x16x32_bf16(hB, fB[0], aI, 0, 0, 0);
            aF = __builtin_amdgcn_mfma_f32_16x16x32_bf16(hA, fA[1], aF, 0, 0, 0);
            aF = __builtin_amdgcn_mfma_f32_16x16x32_bf16(hB, fB[1], aF, 0, 0, 0);
            aG = __builtin_amdgcn_mfma_f32_16x16x32_bf16(hA, fA[2], aG, 0, 0, 0);
            aG = __builtin_amdgcn_mfma_f32_16x16x32_bf16(hB, fB[2], aG, 0, 0, 0);
            aO = __builtin_amdgcn_mfma_f32_16x16x32_bf16(hA, fA[3], aO, 0, 0, 0);
            aO = __builtin_amdgcn_mfma_f32_16x16x32_bf16(hB, fB[3], aO, 0, 0, 0);
            if (it < WIN) {
                #pragma unroll
                for (int j = 0; j < 4; ++j) {
                    float h = cellf(cst[j], aI[j], aF[j], aG[j], aO[j]);
                    h1b[p ^ 1][(kg * 4 + j) * LW + 16 * s + col] = f2bf(h);
                }
            } else {
                #pragma unroll
                for (int j = 0; j < 4; ++j) {
                    float h = cellf(cst[j], aI[j], aF[j], aG[j], aO[j]);
                    h1fin[(size_t)(bbase + kg * 4 + j) * (NFC1 * HS) + f * HS + 16 * s + col] = h;
                }
            }
        }
        __syncthreads();
        p ^= 1;
    }
}

// ---------------- K3: head (mu / logvar / CI bounds) ----------------
__global__ __launch_bounds__(128) void k3_head(
    const float* __restrict__ h1fin, const float* __restrict__ mu_w, const float* __restrict__ mu_b,
    const float* __restrict__ lv_w, const float* __restrict__ lv_b, float* __restrict__ out)
{
    const int b = blockIdx.x, tid = threadIdx.x;
    const float* hrow = h1fin + (size_t)b * (NFC1 * HS);
    float am = 0.f, al = 0.f;
    for (int i = tid; i < NFC1 * HS; i += 128) {
        float h = hrow[i];
        am = fmaf(h, mu_w[i], am);
        al = fmaf(h, lv_w[i], al);
    }
    for (int off = 32; off >= 1; off >>= 1) {
        am += __shfl_down(am, off, 64);
        al += __shfl_down(al, off, 64);
    }
    __shared__ float sm[2], sl[2];
    const int wv = tid >> 6, ln = tid & 63;
    if (ln == 0) { sm[wv] = am; sl[wv] = al; }
    __syncthreads();
    if (tid == 0) {
        float mu = sm[0] + sm[1] + mu_b[0];
        float lv = sl[0] + sl[1] + lv_b[0];
        float sg = expf(0.5f * lv);
        out[b]           = mu - 1.96f * sg;
        out[128 + b]     = mu;
        out[256 + b]     = mu + 1.96f * sg;
        out[384 + b]     = lv;
    }
}

extern "C" void kernel_launch(void* const* d_in, const int* in_sizes, int n_in,
                              void* d_out, int out_size, void* d_ws, size_t ws_size,
                              hipStream_t stream)
{
    const float* x      = (const float*)d_in[0];
    const float* conv_w = (const float*)d_in[1];
    const float* conv_b = (const float*)d_in[2];
    const float* fc1_w  = (const float*)d_in[3];
    const float* fc1_b  = (const float*)d_in[4];
    const float* w_ih0  = (const float*)d_in[5];
    const float* w_ih1  = (const float*)d_in[6];
    const float* w_hh   = (const float*)d_in[7];
    const float* b_lstm = (const float*)d_in[8];
    const float* mu_w   = (const float*)d_in[9];
    const float* mu_b   = (const float*)d_in[10];
    const float* lv_w   = (const float*)d_in[11];
    const float* lv_b   = (const float*)d_in[12];
    float* out = (float*)d_out;

    float* z     = (float*)d_ws;                              // 524288 floats
    float* h1fin = z + (size_t)WIN * NFC1 * BATCH;            // 131072 floats
    unsigned short* w_bf = (unsigned short*)(h1fin + (size_t)BATCH * NFC1 * HS);  // 32*KP bf16

    k0_wconv<<<dim3(NFC1), dim3(256), 0, stream>>>(fc1_w, w_bf);
    k1_conv_fc1<<<dim3(WIN * 8), dim3(128), 0, stream>>>(x, conv_w, conv_b, w_bf, fc1_b, z);
    k2_lstm_mfma<<<dim3(NFC1 * 8), dim3(256), 0, stream>>>(w_ih0, w_ih1, w_hh, b_lstm, z, h1fin);
    k3_head<<<dim3(BATCH), dim3(128), 0, stream>>>(h1fin, mu_w, mu_b, lv_w, lv_b, out);
}

// Round 6
// 86.445 us; speedup vs baseline: 6.5835x; 1.1614x over previous
//
#include <hip/hip_runtime.h>
#include <hip/hip_bf16.h>
#include <math.h>

#define BATCH 128
#define WIN   128      // time steps / conv groups
#define NF    128      // conv spatial length
#define KC    16
#define POOL  65
#define NFC1  32       // number of LSTMs
#define HS    32       // hidden size
#define LW    40       // k2 h-buffer row stride (bf16 elems, 80B)
#define KP    1056     // fc1 K padded to multiple of 32
#define PSTR  1064     // poolb row stride (bf16 elems; 2128B -> conflict-free b128 reads)

typedef float f32x4 __attribute__((ext_vector_type(4)));
typedef short bf16x8 __attribute__((ext_vector_type(8)));

#define LOG2E   1.442695041f
#define LOG2E2  2.885390082f

// gates arrive PRESCALED: i,f,o by -log2e ; g by +2*log2e (folded into weights).
// ei = e^-i, ef = e^-f, eo = e^-o, eg = e^{2g} via single v_exp_f32 each.
// 5 exp2 + 3 rcp + 1 med3; NaN-safe via c clamp.
__device__ __forceinline__ float cellf(float& c, float gi, float gf, float gg, float go) {
    float ei = __builtin_amdgcn_exp2f(gi);
    float ef = __builtin_amdgcn_exp2f(gf);
    float eg = __builtin_amdgcn_exp2f(gg);
    float eo = __builtin_amdgcn_exp2f(go);
    float sf = __builtin_amdgcn_rcpf(1.f + ef);
    c = fmaf(sf, c, (eg - 1.f) * __builtin_amdgcn_rcpf((1.f + ei) * (eg + 1.f)));
    float ec = __builtin_amdgcn_exp2f(__builtin_amdgcn_fmed3f(c, -30.f, 30.f) * LOG2E2);
    return (ec - 1.f) * __builtin_amdgcn_rcpf((1.f + eo) * (ec + 1.f));
}
__device__ __forceinline__ unsigned short f2bf(float x) {
    __hip_bfloat16 h = __float2bfloat16(x);
    unsigned short u; __builtin_memcpy(&u, &h, 2); return u;
}
__device__ __forceinline__ float bf2f(unsigned short u) {
    unsigned int v = ((unsigned int)u) << 16;
    float f; __builtin_memcpy(&f, &v, 4); return f;
}
__device__ __forceinline__ bf16x8 load_row8_scaled(const float* row, float sc) {
    float4 lo = ((const float4*)row)[0];
    float4 hi = ((const float4*)row)[1];
    union { bf16x8 v; unsigned short u[8]; } t;
    t.u[0] = f2bf(lo.x * sc); t.u[1] = f2bf(lo.y * sc); t.u[2] = f2bf(lo.z * sc); t.u[3] = f2bf(lo.w * sc);
    t.u[4] = f2bf(hi.x * sc); t.u[5] = f2bf(hi.y * sc); t.u[6] = f2bf(hi.z * sc); t.u[7] = f2bf(hi.w * sc);
    return t.v;
}

// ---------------- K0: convert fc1_w -> bf16, K-padded [32][KP] ----------------
__global__ __launch_bounds__(256) void k0_wconv(
    const float* __restrict__ fc1_w, unsigned short* __restrict__ w_bf)
{
    const int o = blockIdx.x;
    for (int i = threadIdx.x; i < KP; i += 256) {
        float v = (i < KC * POOL) ? fc1_w[(size_t)o * (KC * POOL) + i] : 0.f;
        w_bf[(size_t)o * KP + i] = f2bf(v);
    }
}

// ---------------- K1: grouped conv1d + relu + maxpool + fc1 (MFMA) ----------------
// grid = 128 w * 8 batch-tiles(16) = 1024 blocks of 128 threads (2 waves).
__global__ __launch_bounds__(128, 2) void k1_conv_fc1(
    const float* __restrict__ x, const float* __restrict__ conv_w, const float* __restrict__ conv_b,
    const unsigned short* __restrict__ w_bf, const float* __restrict__ fc1_b, float* __restrict__ z)
{
    __shared__ __align__(16) unsigned short xp[16][132];     // bf16, xp[b][i] = x[i-1], 0-padded
    __shared__ __align__(16) unsigned short poolb[16 * PSTR];
    __shared__ float cw[KC][3];
    __shared__ float cb[KC];
    __shared__ float fb[NFC1];

    const int w = blockIdx.x >> 3;
    const int bbase = (blockIdx.x & 7) * 16;
    const int tid = threadIdx.x;

    if (tid < KC * 3) cw[tid / 3][tid % 3] = conv_w[(w * KC + tid / 3) * 3 + tid % 3];
    if (tid >= 64 && tid < 64 + KC) cb[tid - 64] = conv_b[w * KC + (tid - 64)];
    if (tid >= 96 && tid < 96 + NFC1) fb[tid - 96] = fc1_b[tid - 96];

    // vectorized x staging: 16 rows x 32 float4
    for (int i = tid; i < 16 * 32; i += 128) {
        int b = i >> 5, q = i & 31;
        float4 v = ((const float4*)(x + (size_t)(bbase + b) * (WIN * NF) + (size_t)w * NF))[q];
        unsigned short* dst = &xp[b][1 + q * 4];
        dst[0] = f2bf(v.x); dst[1] = f2bf(v.y); dst[2] = f2bf(v.z); dst[3] = f2bf(v.w);
    }
    if (tid < 16) { xp[tid][0] = 0; xp[tid][129] = 0; xp[tid][130] = 0; xp[tid][131] = 0; }
    __syncthreads();

    // conv + relu + pool: thread -> (b0, k) and (b0+8, k); sliding window over xp
    {
        const int b0 = tid >> 4;       // 0..7
        const int k = tid & 15;
        const float w0 = cw[k][0], w1 = cw[k][1], w2 = cw[k][2], bb = cb[k];
        #pragma unroll
        for (int half = 0; half < 2; ++half) {
            const int b = b0 + half * 8;
            float v1 = 0.f;
            float v2 = bf2f(xp[b][0]);
            float v3 = bf2f(xp[b][1]);
            unsigned short* prow = &poolb[b * PSTR + k * POOL];
            #pragma unroll 5
            for (int j = 0; j < POOL; ++j) {
                float v0 = v1; v1 = v2; v2 = v3;
                v3 = bf2f(xp[b][2 * j + 2]);
                float oa = bb + w0 * v0 + w1 * v1 + w2 * v2;   // out(2j-1)
                float ob = bb + w0 * v1 + w1 * v2 + w2 * v3;   // out(2j)
                float m = 0.f;                                  // relu floor
                if (j > 0)        m = fmaxf(m, oa);
                if (j < POOL - 1) m = fmaxf(m, ob);
                prow[j] = f2bf(m);
            }
        }
    }
    // zero K-pad tail (cols 1040..1055)
    for (int i = tid; i < 16 * (KP - KC * POOL); i += 128) {
        int b = i >> 4, c = i & 15;
        poolb[b * PSTR + KC * POOL + c] = 0;
    }
    __syncthreads();

    // fc1 MFMA: wave wid -> ntile = wid (o = wid*16+col)
    const int lane = tid & 63;
    const int wid = tid >> 6;
    const int col = lane & 15;
    const int kg = lane >> 4;
    const int g = wid * 16 + col;
    f32x4 acc;
    {
        float bias = fb[g];
        acc[0] = bias; acc[1] = bias; acc[2] = bias; acc[3] = bias;
    }
    const unsigned short* wrow = w_bf + (size_t)g * KP;
    #pragma unroll 4
    for (int ks = 0; ks < KP / 32; ++ks) {
        bf16x8 aP = *(const bf16x8*)&poolb[col * PSTR + ks * 32 + kg * 8];
        bf16x8 bW = *(const bf16x8*)&wrow[ks * 32 + kg * 8];
        acc = __builtin_amdgcn_mfma_f32_16x16x32_bf16(aP, bW, acc, 0, 0, 0);
    }
    float4 st; st.x = acc[0]; st.y = acc[1]; st.z = acc[2]; st.w = acc[3];
    *(float4*)&z[(size_t)w * (NFC1 * BATCH) + (size_t)g * BATCH + bbase + kg * 4] = st;
}

// ---------------- K2: 2-layer LSTM via bf16 MFMA, layer-pipelined ----------------
// grid = 32 f * 8 batch-tiles(16) = 256 blocks of 256 threads (4 waves).
// waves 0,1 = layer0 (s halves); waves 2,3 = layer1 one step behind.
// Static parity double-buffer (named LDS arrays), 2x-unrolled loop, 1 barrier/step.
// Weights prescaled into exp2 domain (see cellf).
__global__ __launch_bounds__(256, 1) void k2_lstm_mfma(
    const float* __restrict__ w_ih0, const float* __restrict__ w_ih1,
    const float* __restrict__ w_hh, const float* __restrict__ b_lstm,
    const float* __restrict__ z, float* __restrict__ h1fin)
{
    __shared__ float zs[WIN][16];
    __shared__ __align__(16) unsigned short h0b0[16 * LW];
    __shared__ __align__(16) unsigned short h0b1[16 * LW];
    __shared__ __align__(16) unsigned short h1b0[16 * LW];
    __shared__ __align__(16) unsigned short h1b1[16 * LW];

    const int f = blockIdx.x >> 3;
    const int bbase = (blockIdx.x & 7) * 16;
    const int tid = threadIdx.x;
    const int wid = tid >> 6, lane = tid & 63;
    const bool isL0 = (wid < 2);
    const int s = wid & 1;
    const int col = lane & 15;
    const int kg = lane >> 4;

    // vectorized z staging: zs[t][0..15] = z[t][f][bbase..bbase+15]
    for (int i = tid; i < WIN * 4; i += 256) {
        int t = i >> 2, q = i & 3;
        ((float4*)&zs[t][0])[q] = ((const float4*)&z[(size_t)t * (NFC1 * BATCH) + f * BATCH + bbase])[q];
    }
    for (int i = tid; i < 16 * LW; i += 256) {
        h0b0[i] = 0; h0b1[i] = 0; h1b0[i] = 0; h1b1[i] = 0;
    }

    // gate-type scale factors (exp2 domain)
    const float gsc[4] = { -LOG2E, -LOG2E, LOG2E2, -LOG2E };

    const float* WA = isL0 ? (w_hh + (size_t)f * 4096)
                           : (w_ih1 + (size_t)f * 4096);
    const float* WV = w_hh + (size_t)(NFC1 + f) * 4096;
    bf16x8 fA[4], fB[4];
    float bias[4], wi0[4];
    const int loff = isL0 ? 0 : (NFC1 * 128);
    #pragma unroll
    for (int gi = 0; gi < 4; ++gi) {
        int nt = gi * 2 + s;
        int g = nt * 16 + col;
        fA[gi] = load_row8_scaled(WA + g * 32 + kg * 8, gsc[gi]);
        if (!isL0) fB[gi] = load_row8_scaled(WV + g * 32 + kg * 8, gsc[gi]);
        bias[gi] = b_lstm[loff + f * 128 + g] * gsc[gi];
        wi0[gi] = w_ih0[f * 128 + g] * gsc[gi];
    }
    __syncthreads();

    const int hread = col * LW + kg * 8;
    const int hw0 = (kg * 4 + 0) * LW + 16 * s + col;
    float cst[4] = {0.f, 0.f, 0.f, 0.f};
    f32x4 zv = *(const f32x4*)&zs[0][kg * 4];

    auto body = [&](int it, const unsigned short* h0r, unsigned short* h0w,
                            const unsigned short* h1r, unsigned short* h1w) {
        if (isL0) {
            if (it < WIN) {
                bf16x8 hA = *(const bf16x8*)&h0r[hread];
                f32x4 aI, aF, aG, aO;
                #pragma unroll
                for (int j = 0; j < 4; ++j) {
                    aI[j] = fmaf(zv[j], wi0[0], bias[0]);
                    aF[j] = fmaf(zv[j], wi0[1], bias[1]);
                    aG[j] = fmaf(zv[j], wi0[2], bias[2]);
                    aO[j] = fmaf(zv[j], wi0[3], bias[3]);
                }
                aI = __builtin_amdgcn_mfma_f32_16x16x32_bf16(hA, fA[0], aI, 0, 0, 0);
                aF = __builtin_amdgcn_mfma_f32_16x16x32_bf16(hA, fA[1], aF, 0, 0, 0);
                aG = __builtin_amdgcn_mfma_f32_16x16x32_bf16(hA, fA[2], aG, 0, 0, 0);
                aO = __builtin_amdgcn_mfma_f32_16x16x32_bf16(hA, fA[3], aO, 0, 0, 0);
                if (it + 1 < WIN) zv = *(const f32x4*)&zs[it + 1][kg * 4];
                #pragma unroll
                for (int j = 0; j < 4; ++j) {
                    float h = cellf(cst[j], aI[j], aF[j], aG[j], aO[j]);
                    h0w[hw0 + j * LW] = f2bf(h);
                }
            }
        } else {
            if (it >= 1) {
                bf16x8 hA = *(const bf16x8*)&h0r[hread];
                bf16x8 hB = *(const bf16x8*)&h1r[hread];
                f32x4 aI, aF, aG, aO;
                #pragma unroll
                for (int j = 0; j < 4; ++j) { aI[j] = bias[0]; aF[j] = bias[1]; aG[j] = bias[2]; aO[j] = bias[3]; }
                aI = __builtin_amdgcn_mfma_f32_16x16x32_bf16(hA, fA[0], aI, 0, 0, 0);
                aI = __builtin_amdgcn_mfma_f32_16x16x32_bf16(hB, fB[0], aI, 0, 0, 0);
                aF = __builtin_amdgcn_mfma_f32_16x16x32_bf16(hA, fA[1], aF, 0, 0, 0);
                aF = __builtin_amdgcn_mfma_f32_16x16x32_bf16(hB, fB[1], aF, 0, 0, 0);
                aG = __builtin_amdgcn_mfma_f32_16x16x32_bf16(hA, fA[2], aG, 0, 0, 0);
                aG = __builtin_amdgcn_mfma_f32_16x16x32_bf16(hB, fB[2], aG, 0, 0, 0);
                aO = __builtin_amdgcn_mfma_f32_16x16x32_bf16(hA, fA[3], aO, 0, 0, 0);
                aO = __builtin_amdgcn_mfma_f32_16x16x32_bf16(hB, fB[3], aO, 0, 0, 0);
                if (it < WIN) {
                    #pragma unroll
                    for (int j = 0; j < 4; ++j) {
                        float h = cellf(cst[j], aI[j], aF[j], aG[j], aO[j]);
                        h1w[hw0 + j * LW] = f2bf(h);
                    }
                } else {
                    #pragma unroll
                    for (int j = 0; j < 4; ++j) {
                        float h = cellf(cst[j], aI[j], aF[j], aG[j], aO[j]);
                        h1fin[(size_t)(bbase + kg * 4 + j) * (NFC1 * HS) + f * HS + 16 * s + col] = h;
                    }
                }
            }
        }
    };

    body(0, h0b0, h0b1, h1b0, h1b1);
    __syncthreads();
    #pragma unroll 1
    for (int it = 1; it <= WIN; it += 2) {
        body(it,     h0b1, h0b0, h1b1, h1b0);
        __syncthreads();
        body(it + 1, h0b0, h0b1, h1b0, h1b1);
        __syncthreads();
    }
}

// ---------------- K3: head (mu / logvar / CI bounds) ----------------
__global__ __launch_bounds__(128) void k3_head(
    const float* __restrict__ h1fin, const float* __restrict__ mu_w, const float* __restrict__ mu_b,
    const float* __restrict__ lv_w, const float* __restrict__ lv_b, float* __restrict__ out)
{
    const int b = blockIdx.x, tid = threadIdx.x;
    const float* hrow = h1fin + (size_t)b * (NFC1 * HS);
    float am = 0.f, al = 0.f;
    for (int i = tid; i < NFC1 * HS; i += 128) {
        float h = hrow[i];
        am = fmaf(h, mu_w[i], am);
        al = fmaf(h, lv_w[i], al);
    }
    for (int off = 32; off >= 1; off >>= 1) {
        am += __shfl_down(am, off, 64);
        al += __shfl_down(al, off, 64);
    }
    __shared__ float sm[2], sl[2];
    const int wv = tid >> 6, ln = tid & 63;
    if (ln == 0) { sm[wv] = am; sl[wv] = al; }
    __syncthreads();
    if (tid == 0) {
        float mu = sm[0] + sm[1] + mu_b[0];
        float lv = sl[0] + sl[1] + lv_b[0];
        float sg = expf(0.5f * lv);
        out[b]           = mu - 1.96f * sg;
        out[128 + b]     = mu;
        out[256 + b]     = mu + 1.96f * sg;
        out[384 + b]     = lv;
    }
}

extern "C" void kernel_launch(void* const* d_in, const int* in_sizes, int n_in,
                              void* d_out, int out_size, void* d_ws, size_t ws_size,
                              hipStream_t stream)
{
    const float* x      = (const float*)d_in[0];
    const float* conv_w = (const float*)d_in[1];
    const float* conv_b = (const float*)d_in[2];
    const float* fc1_w  = (const float*)d_in[3];
    const float* fc1_b  = (const float*)d_in[4];
    const float* w_ih0  = (const float*)d_in[5];
    const float* w_ih1  = (const float*)d_in[6];
    const float* w_hh   = (const float*)d_in[7];
    const float* b_lstm = (const float*)d_in[8];
    const float* mu_w   = (const float*)d_in[9];
    const float* mu_b   = (const float*)d_in[10];
    const float* lv_w   = (const float*)d_in[11];
    const float* lv_b   = (const float*)d_in[12];
    float* out = (float*)d_out;

    float* z     = (float*)d_ws;                              // 524288 floats
    float* h1fin = z + (size_t)WIN * NFC1 * BATCH;            // 131072 floats
    unsigned short* w_bf = (unsigned short*)(h1fin + (size_t)BATCH * NFC1 * HS);  // 32*KP bf16

    k0_wconv<<<dim3(NFC1), dim3(256), 0, stream>>>(fc1_w, w_bf);
    k1_conv_fc1<<<dim3(WIN * 8), dim3(128), 0, stream>>>(x, conv_w, conv_b, w_bf, fc1_b, z);
    k2_lstm_mfma<<<dim3(NFC1 * 8), dim3(256), 0, stream>>>(w_ih0, w_ih1, w_hh, b_lstm, z, h1fin);
    k3_head<<<dim3(BATCH), dim3(128), 0, stream>>>(h1fin, mu_w, mu_b, lv_w, lv_b, out);
}